// Round 1
// baseline (125.456 us; speedup 1.0000x reference)
//
#include <hip/hip_runtime.h>

#define HW 512
#define KW 11
#define PADR 5
#define OUT_PER_STRIP 54   // 64-lane wave minus 5-lane halo each side
#define NSTRIP 10          // ceil(512/54)
#define NSEG 8
#define ROWS_PER_SEG 64    // 512/8
#define WAVES_PER_BLOCK 4

__global__ __launch_bounds__(256)
void std_loss_kernel(const float* __restrict__ pred,
                     const float* __restrict__ targ,
                     float* __restrict__ out, float invN)
{
    const int lane = threadIdx.x & 63;
    const int wib  = threadIdx.x >> 6;
    const int wid  = blockIdx.x * WAVES_PER_BLOCK + wib;

    const int img   = wid / (NSTRIP * NSEG);
    const int rem   = wid - img * (NSTRIP * NSEG);
    const int strip = rem / NSEG;
    const int seg   = rem - strip * NSEG;

    const float* T = targ + (size_t)img * (HW * HW);
    const float* P = pred + (size_t)img * (HW * HW);

    // lane's padded column; clamp implements replicate padding in x
    const int oxp = strip * OUT_PER_STRIP - PADR + lane;
    const int col = min(max(oxp, 0), HW - 1);
    const bool valid = (lane >= PADR) && (lane < PADR + OUT_PER_STRIP) && (oxp < HW);

    const int y0 = seg * ROWS_PER_SEG;
    const int y1 = y0 + ROWS_PER_SEG;

    // vertical 11-row running sums for window centered at y0 (replicate in y via clamp)
    float vs = 0.f, vq = 0.f;
    #pragma unroll
    for (int dy = -PADR; dy <= PADR; ++dy) {
        int ry = min(max(y0 + dy, 0), HW - 1);
        float v = T[ry * HW + col];
        vs += v; vq += v * v;
    }

    float acc = 0.f;
    for (int y = y0; y < y1; ++y) {
        // wave-wide inclusive prefix sums of the vertical sums
        float ps = vs, pq = vq;
        #pragma unroll
        for (int off = 1; off < 64; off <<= 1) {
            float a = __shfl_up(ps, off, 64);
            float b = __shfl_up(pq, off, 64);
            if (lane >= off) { ps += a; pq += b; }
        }
        // horizontal box = P[l+5] - P[l-6]
        int hi = min(lane + PADR, 63);
        int lo = lane - PADR - 1;
        float bs = __shfl(ps, hi, 64);
        float bq = __shfl(pq, hi, 64);
        float cs = __shfl(ps, max(lo, 0), 64);
        float cq = __shfl(pq, max(lo, 0), 64);
        if (lo < 0) { cs = 0.f; cq = 0.f; }
        bs -= cs; bq -= cq;

        const float inv = 1.0f / (KW * KW);
        float m   = bs * inv;
        float var = fmaf(bq, inv, -m * m);
        float sd  = sqrtf(fmaxf(var, 0.f));
        float w   = fmaf(fminf(sd, 0.4f), 5.0f, 1.0f);

        if (valid) {
            float pv = P[y * HW + col];   // streams from HBM
            float tv = T[y * HW + col];   // L1/L2 hit (in the live window)
            acc += fabsf(pv - tv) * w;
        }

        // slide vertical window: +row clamp(y+6), -row clamp(y-5)
        int ryn = min(y + 1 + PADR, HW - 1);
        int ryo = max(y - PADR, 0);
        float vn = T[ryn * HW + col];     // streams from HBM
        float vo = T[ryo * HW + col];     // L1 hit (read 11 rows ago)
        vs += vn - vo;
        vq += vn * vn - vo * vo;
    }

    // wave reduce
    #pragma unroll
    for (int off = 32; off > 0; off >>= 1)
        acc += __shfl_down(acc, off, 64);

    __shared__ float wsum[WAVES_PER_BLOCK];
    if (lane == 0) wsum[wib] = acc;
    __syncthreads();
    if (threadIdx.x == 0) {
        float s = 0.f;
        #pragma unroll
        for (int i = 0; i < WAVES_PER_BLOCK; ++i) s += wsum[i];
        atomicAdd(out, s * invN);
    }
}

extern "C" void kernel_launch(void* const* d_in, const int* in_sizes, int n_in,
                              void* d_out, int out_size, void* d_ws, size_t ws_size,
                              hipStream_t stream) {
    const float* pred = (const float*)d_in[0];
    const float* targ = (const float*)d_in[1];
    float* out = (float*)d_out;

    const int nimg = in_sizes[1] / (HW * HW);       // 96 for (32,3,512,512)
    const float invN = 1.0f / (float)in_sizes[1];

    hipMemsetAsync(out, 0, sizeof(float), stream);  // capture-legal memset node

    const int nblocks = nimg * NSTRIP * NSEG / WAVES_PER_BLOCK;  // 1920
    std_loss_kernel<<<nblocks, 256, 0, stream>>>(pred, targ, out, invN);
}

// Round 2
// 80.623 us; speedup vs baseline: 1.5561x; 1.5561x over previous
//
#include <hip/hip_runtime.h>

#define HW 512
#define PADR 5
#define SEGS 32          // segments per image
#define ROWS 16          // HW/SEGS rows per segment
#define WPB 4            // waves per block (adjacent segments -> halo reuse in L1/L2)

__device__ __forceinline__ void load8(const float* __restrict__ p, float v[8]) {
    float4 a = *(const float4*)p;
    float4 b = *(const float4*)(p + 4);
    v[0]=a.x; v[1]=a.y; v[2]=a.z; v[3]=a.w;
    v[4]=b.x; v[5]=b.y; v[6]=b.z; v[7]=b.w;
}

__global__ __launch_bounds__(256)
void std_loss_kernel(const float* __restrict__ pred,
                     const float* __restrict__ targ,
                     float* __restrict__ out, float invN)
{
    const int lane = threadIdx.x & 63;
    const int wib  = threadIdx.x >> 6;
    const int wid  = blockIdx.x * WPB + wib;
    const int img  = wid / SEGS;
    const int seg  = wid - img * SEGS;

    const float* T = targ + (size_t)img * (HW*HW);
    const float* P = pred + (size_t)img * (HW*HW);

    const int c0 = lane * 8;                 // 8 owned columns; wave covers full row
    const int y0 = seg * ROWS;
    const int y1 = y0 + ROWS;

    // init vertical 11-row window sums centered at y0 (replicate-y via clamp)
    float vs[8], vq[8];
    #pragma unroll
    for (int i = 0; i < 8; ++i) { vs[i] = 0.f; vq[i] = 0.f; }
    #pragma unroll
    for (int dy = -PADR; dy <= PADR; ++dy) {
        int ry = min(max(y0 + dy, 0), HW - 1);
        float t[8];
        load8(T + ry*HW + c0, t);
        #pragma unroll
        for (int i = 0; i < 8; ++i) { vs[i] += t[i]; vq[i] += t[i]*t[i]; }
    }

    const float inv = 1.0f / 121.0f;
    float acc = 0.f;

    for (int y = y0; y < y1; ++y) {
        // issue all loads up-front so VMEM latency overlaps shfl/compute
        float tv[8], pv[8], vn[8], vo[8];
        load8(T + y*HW + c0, tv);                          // L1/L2 hit (in window)
        load8(P + y*HW + c0, pv);                          // HBM stream
        int ryn = min(y + PADR + 1, HW - 1);
        int ryo = max(y - PADR, 0);
        load8(T + ryn*HW + c0, vn);                        // HBM stream
        load8(T + ryo*HW + c0, vo);                        // L1/L2 hit

        // neighbor exchange: prev lane's vs[2..7], next lane's vs[0..4]
        float es[19], eq[19];
        #pragma unroll
        for (int j = 0; j < 6; ++j) {
            float a = __shfl_up(vs[j+2], 1, 64);
            float b = __shfl_up(vq[j+2], 1, 64);
            es[j] = (lane == 0) ? vs[0] : a;               // replicate-x left edge
            eq[j] = (lane == 0) ? vq[0] : b;
        }
        #pragma unroll
        for (int j = 0; j < 8; ++j) { es[6+j] = vs[j]; eq[6+j] = vq[j]; }
        #pragma unroll
        for (int j = 0; j < 5; ++j) {
            float a = __shfl_down(vs[j], 1, 64);
            float b = __shfl_down(vq[j], 1, 64);
            es[14+j] = (lane == 63) ? vs[7] : a;           // replicate-x right edge
            eq[14+j] = (lane == 63) ? vq[7] : b;
        }

        // in-lane sliding 11-box over ext window: col i -> es[i+1 .. i+11]
        float bs = 0.f, bq = 0.f;
        #pragma unroll
        for (int j = 1; j <= 11; ++j) { bs += es[j]; bq += eq[j]; }
        #pragma unroll
        for (int i = 0; i < 8; ++i) {
            if (i > 0) { bs += es[i+11] - es[i]; bq += eq[i+11] - eq[i]; }
            float m   = bs * inv;
            float var = fmaf(bq, inv, -m*m);
            float sd  = sqrtf(fmaxf(var, 0.f));
            float w   = fmaf(fminf(sd, 0.4f), 5.0f, 1.0f);
            acc += fabsf(pv[i] - tv[i]) * w;
        }

        // slide vertical window down one row
        #pragma unroll
        for (int i = 0; i < 8; ++i) {
            vs[i] += vn[i] - vo[i];
            vq[i] += vn[i]*vn[i] - vo[i]*vo[i];
        }
    }

    // wave reduce
    #pragma unroll
    for (int off = 32; off > 0; off >>= 1)
        acc += __shfl_down(acc, off, 64);

    __shared__ float wsum[WPB];
    if (lane == 0) wsum[wib] = acc;
    __syncthreads();
    if (threadIdx.x == 0) {
        float s = 0.f;
        #pragma unroll
        for (int i = 0; i < WPB; ++i) s += wsum[i];
        atomicAdd(out, s * invN);
    }
}

extern "C" void kernel_launch(void* const* d_in, const int* in_sizes, int n_in,
                              void* d_out, int out_size, void* d_ws, size_t ws_size,
                              hipStream_t stream) {
    const float* pred = (const float*)d_in[0];
    const float* targ = (const float*)d_in[1];
    float* out = (float*)d_out;

    const int nimg = in_sizes[1] / (HW * HW);       // 96 for (32,3,512,512)
    const float invN = 1.0f / (float)in_sizes[1];

    hipMemsetAsync(out, 0, sizeof(float), stream);  // capture-legal memset node

    const int nblocks = nimg * SEGS / WPB;          // 768
    std_loss_kernel<<<nblocks, 256, 0, stream>>>(pred, targ, out, invN);
}